// Round 3
// baseline (3516.050 us; speedup 1.0000x reference)
//
#include <hip/hip_runtime.h>
#include <hip/hip_bf16.h>

typedef __attribute__((ext_vector_type(8))) __bf16 bf16x8;
typedef __attribute__((ext_vector_type(4))) float f32x4;

#define MFMA(a, b, c) __builtin_amdgcn_mfma_f32_16x16x32_bf16((a), (b), (c), 0, 0, 0)

// Slow path: B-fragment from fp32 global weight W[k][n], row stride S (elements).
template <int S>
static __device__ __forceinline__ bf16x8 bfragG(const float* __restrict__ W, int k0, int n) {
    const float* p = W + (size_t)k0 * S + n;
    bf16x8 b;
#pragma unroll
    for (int j = 0; j < 8; ++j) b[j] = (__bf16)p[(size_t)j * S];
    return b;
}

// Fast path: B-fragment from bf16 transposed weight WT[n][k], row stride KS. One 16B load.
static __device__ __forceinline__ bf16x8 bfragT(const unsigned short* __restrict__ WT,
                                                size_t rowoff, int k0) {
    return *(const bf16x8*)((const __bf16*)WT + rowoff + k0);
}

// ---------------------------------------------------------------------------
// Weight transpose+cvt: in fp32 [B][K][N] -> out bf16 [B][N][K]. 64x64 tiles.
// ---------------------------------------------------------------------------
__global__ __launch_bounds__(256) void tKern(const float* __restrict__ in,
                                             unsigned short* __restrict__ outp,
                                             int K, int N) {
    __shared__ float tile[64][65];
    const int tk = blockIdx.x, tn = blockIdx.y, bz = blockIdx.z;
    const size_t base = (size_t)bz * K * N;
    const int r = threadIdx.x >> 2, c0 = (threadIdx.x & 3) * 16;
    const float* ip = in + base + (size_t)(tk * 64 + r) * N + tn * 64 + c0;
#pragma unroll
    for (int j = 0; j < 16; ++j) tile[r][c0 + j] = ip[j];
    __syncthreads();
    __bf16* op = (__bf16*)outp + base + (size_t)(tn * 64 + r) * K + tk * 64 + c0;
#pragma unroll
    for (int j = 0; j < 16; ++j) op[j] = (__bf16)tile[c0 + j][r];
}

// ---------------------------------------------------------------------------
// Kernel A: x2 = x + MHA(LN1(x)) ; writes x2 to out (fp32)
// 64 rows (= 4 sequences of T=16) per block, 256 threads (4 waves).
// BF=true: weights come from bf16-transposed ws arrays; else fp32 strided.
// ---------------------------------------------------------------------------
template <bool BF>
__global__ __launch_bounds__(256) void kA(
    const float* __restrict__ x,
    const float* __restrict__ Wq, const float* __restrict__ bq,
    const float* __restrict__ Wk, const float* __restrict__ bk,
    const float* __restrict__ Wv, const float* __restrict__ bv,
    const float* __restrict__ Wo, const float* __restrict__ bo,
    const float* __restrict__ ln1g, const float* __restrict__ ln1b,
    const unsigned short* __restrict__ qT, const unsigned short* __restrict__ kT,
    const unsigned short* __restrict__ vT, const unsigned short* __restrict__ oT,
    float* __restrict__ out)
{
    __shared__ __bf16 h_lds[64][520];   // LN1(x) tile, bf16
    __shared__ __bf16 q_lds[64][72];    // per-head Q (head-local cols 0..63)
    __shared__ __bf16 k_lds[64][72];    // per-head K
    __shared__ __bf16 vT_lds[64][88];   // per-head V^T: [e][t'_global]; cols 64..79 zero
    __shared__ __bf16 c_lds[64][72];    // per-head ctx
    __shared__ __bf16 P_lds[4][16][40]; // per-seq probs, cols 16..31 zero (K-pad)

    const int tid = threadIdx.x;
    const int wave = tid >> 6;
    const int lane = tid & 63;
    const int g = lane >> 4;
    const int lq = lane & 15;
    const int kb = g * 8;
    const size_t R0 = (size_t)blockIdx.x * 64;

    // zero the pad regions that get multiplied by MFMA
    for (int i = tid; i < 4 * 16 * 40; i += 256) ((__bf16*)P_lds)[i] = (__bf16)0.f;
    for (int i = tid; i < 64 * 24; i += 256) vT_lds[i / 24][64 + (i % 24)] = (__bf16)0.f;

    // ---- LN1: 4 threads per row ----
    {
        const int row = tid >> 2, sub = tid & 3;
        const float4* xr = (const float4*)(x + (R0 + row) * 512) + sub * 32;
        float s = 0.f, ss = 0.f;
#pragma unroll
        for (int i = 0; i < 32; ++i) {
            float4 v = xr[i];
            s += (v.x + v.y) + (v.z + v.w);
            ss += (v.x * v.x + v.y * v.y) + (v.z * v.z + v.w * v.w);
        }
        s += __shfl_xor(s, 1);  ss += __shfl_xor(ss, 1);
        s += __shfl_xor(s, 2);  ss += __shfl_xor(ss, 2);
        const float mu = s * (1.f / 512.f);
        const float rs = rsqrtf(ss * (1.f / 512.f) - mu * mu + 1e-5f);
        const float4* gp = (const float4*)ln1g + sub * 32;
        const float4* bp = (const float4*)ln1b + sub * 32;
#pragma unroll
        for (int i = 0; i < 32; ++i) {
            float4 v = xr[i];
            float4 gg = gp[i];
            float4 bb = bp[i];
            const int c0 = sub * 128 + i * 4;
            h_lds[row][c0 + 0] = (__bf16)((v.x - mu) * rs * gg.x + bb.x);
            h_lds[row][c0 + 1] = (__bf16)((v.y - mu) * rs * gg.y + bb.y);
            h_lds[row][c0 + 2] = (__bf16)((v.z - mu) * rs * gg.z + bb.z);
            h_lds[row][c0 + 3] = (__bf16)((v.w - mu) * rs * gg.w + bb.w);
        }
    }
    __syncthreads();

    f32x4 x2acc[8][4];
#pragma unroll
    for (int i = 0; i < 8; ++i)
#pragma unroll
        for (int m = 0; m < 4; ++m) x2acc[i][m] = (f32x4){0.f, 0.f, 0.f, 0.f};

    for (int h = 0; h < 8; ++h) {
        const float* Wqh = Wq + (size_t)h * (512 * 64);
        const float* Wkh = Wk + (size_t)h * (512 * 64);
        const float* Wvh = Wv + (size_t)h * (512 * 64);
        const int nl = wave * 16 + lq;  // head-local output col (n-split by wave)

        // ---- Q ----
        {
            f32x4 acc[4] = {};
#pragma unroll 2
            for (int kt = 0; kt < 16; ++kt) {
                bf16x8 bf;
                if constexpr (BF) bf = bfragT(qT, ((size_t)h * 64 + nl) * 512, kt * 32 + kb);
                else              bf = bfragG<64>(Wqh, kt * 32 + kb, nl);
#pragma unroll
                for (int m = 0; m < 4; ++m) {
                    bf16x8 af = *(const bf16x8*)&h_lds[m * 16 + lq][kt * 32 + kb];
                    acc[m] = MFMA(af, bf, acc[m]);
                }
            }
            const float bia = bq[h * 64 + nl];
#pragma unroll
            for (int m = 0; m < 4; ++m)
#pragma unroll
                for (int r = 0; r < 4; ++r)
                    q_lds[m * 16 + g * 4 + r][nl] = (__bf16)(acc[m][r] + bia);
        }
        // ---- K ----
        {
            f32x4 acc[4] = {};
#pragma unroll 2
            for (int kt = 0; kt < 16; ++kt) {
                bf16x8 bf;
                if constexpr (BF) bf = bfragT(kT, ((size_t)h * 64 + nl) * 512, kt * 32 + kb);
                else              bf = bfragG<64>(Wkh, kt * 32 + kb, nl);
#pragma unroll
                for (int m = 0; m < 4; ++m) {
                    bf16x8 af = *(const bf16x8*)&h_lds[m * 16 + lq][kt * 32 + kb];
                    acc[m] = MFMA(af, bf, acc[m]);
                }
            }
            const float bia = bk[h * 64 + nl];
#pragma unroll
            for (int m = 0; m < 4; ++m)
#pragma unroll
                for (int r = 0; r < 4; ++r)
                    k_lds[m * 16 + g * 4 + r][nl] = (__bf16)(acc[m][r] + bia);
        }
        // ---- V (store transposed: vT[e][t'_global]) ----
        {
            f32x4 acc[4] = {};
#pragma unroll 2
            for (int kt = 0; kt < 16; ++kt) {
                bf16x8 bf;
                if constexpr (BF) bf = bfragT(vT, ((size_t)h * 64 + nl) * 512, kt * 32 + kb);
                else              bf = bfragG<64>(Wvh, kt * 32 + kb, nl);
#pragma unroll
                for (int m = 0; m < 4; ++m) {
                    bf16x8 af = *(const bf16x8*)&h_lds[m * 16 + lq][kt * 32 + kb];
                    acc[m] = MFMA(af, bf, acc[m]);
                }
            }
            const float bia = bv[h * 64 + nl];
#pragma unroll
            for (int m = 0; m < 4; ++m)
#pragma unroll
                for (int r = 0; r < 4; ++r)
                    vT_lds[nl][m * 16 + g * 4 + r] = (__bf16)(acc[m][r] + bia);
        }
        __syncthreads();

        // ---- attention: wave w handles sequence w (rows w*16..w*16+15) ----
        {
            const int s0 = wave * 16;
            f32x4 sc = {};
#pragma unroll
            for (int kt = 0; kt < 2; ++kt) {
                bf16x8 af = *(const bf16x8*)&q_lds[s0 + lq][kt * 32 + kb];
                bf16x8 bf = *(const bf16x8*)&k_lds[s0 + lq][kt * 32 + kb];
                sc = MFMA(af, bf, sc);
            }
            // sc[r]: score[t = g*4+r][t' = lq]; causal softmax across 16-lane groups
#pragma unroll
            for (int r = 0; r < 4; ++r) {
                const int t = g * 4 + r;
                float sv = (lq <= t) ? sc[r] * 0.125f : -3.0e38f;
                float mx = sv;
                mx = fmaxf(mx, __shfl_xor(mx, 1));
                mx = fmaxf(mx, __shfl_xor(mx, 2));
                mx = fmaxf(mx, __shfl_xor(mx, 4));
                mx = fmaxf(mx, __shfl_xor(mx, 8));
                const float e = __expf(sv - mx);
                float sm = e;
                sm += __shfl_xor(sm, 1);
                sm += __shfl_xor(sm, 2);
                sm += __shfl_xor(sm, 4);
                sm += __shfl_xor(sm, 8);
                P_lds[wave][t][lq] = (__bf16)(e / sm);
            }
            // ctx = P(16x16, K-padded to 32 with zeros) @ V(16x64)
            f32x4 ca[4] = {};
            bf16x8 pa = *(const bf16x8*)&P_lds[wave][lq][kb];
#pragma unroll
            for (int nt = 0; nt < 4; ++nt) {
                bf16x8 bf = *(const bf16x8*)&vT_lds[nt * 16 + lq][s0 + kb];
                ca[nt] = MFMA(pa, bf, ca[nt]);
            }
#pragma unroll
            for (int nt = 0; nt < 4; ++nt)
#pragma unroll
                for (int r = 0; r < 4; ++r)
                    c_lds[s0 + g * 4 + r][nt * 16 + lq] = (__bf16)ca[nt][r];
        }
        __syncthreads();

        // ---- accumulate x2 += ctx_h @ Wo[h*64:(h+1)*64, :]  (n-split by wave) ----
        const float* Woh = Wo + (size_t)h * 64 * 512;
#pragma unroll
        for (int kt = 0; kt < 2; ++kt) {
            bf16x8 af[4];
#pragma unroll
            for (int m = 0; m < 4; ++m)
                af[m] = *(const bf16x8*)&c_lds[m * 16 + lq][kt * 32 + kb];
#pragma unroll
            for (int i = 0; i < 8; ++i) {
                const int ng = (i * 4 + wave) * 16 + lq;
                bf16x8 bf;
                if constexpr (BF) bf = bfragT(oT, (size_t)ng * 512, h * 64 + kt * 32 + kb);
                else              bf = bfragG<512>(Woh, kt * 32 + kb, ng);
#pragma unroll
                for (int m = 0; m < 4; ++m)
                    x2acc[i][m] = MFMA(af[m], bf, x2acc[i][m]);
            }
        }
        // no barrier needed: next phase writes q/k/vT only; the post-QKV barrier
        // of the next head orders those writes w.r.t. this head's c_lds reads.
    }

    // ---- epilogue: x2 = acc + bo + x ----
#pragma unroll
    for (int i = 0; i < 8; ++i) {
        const int n2 = (i * 4 + wave) * 16 + lq;
        const float bov = bo[n2];
#pragma unroll
        for (int m = 0; m < 4; ++m)
#pragma unroll
            for (int r = 0; r < 4; ++r) {
                const size_t row = R0 + m * 16 + g * 4 + r;
                out[row * 512 + n2] = x2acc[i][m][r] + bov + x[row * 512 + n2];
            }
    }
}

// ---------------------------------------------------------------------------
// Kernel B: io = io + FF(LN2(io)), in place on d_out (row-local, safe).
// 64 rows per block, 256 threads (4 waves).
// ---------------------------------------------------------------------------
template <bool BF>
__global__ __launch_bounds__(256) void kB(
    const float* __restrict__ W1, const float* __restrict__ fb1,
    const float* __restrict__ W2, const float* __restrict__ fb2,
    const float* __restrict__ ln2g, const float* __restrict__ ln2b,
    const unsigned short* __restrict__ w1T, const unsigned short* __restrict__ w2T,
    float* __restrict__ io)
{
    __shared__ __bf16 h_lds[64][520];  // LN2(x2), bf16
    __shared__ __bf16 a_lds[64][72];   // relu chunk (Nc=64)

    const int tid = threadIdx.x;
    const int wave = tid >> 6;
    const int lane = tid & 63;
    const int g = lane >> 4;
    const int lq = lane & 15;
    const int kb = g * 8;
    const size_t R0 = (size_t)blockIdx.x * 64;

    // ---- LN2 ----
    {
        const int row = tid >> 2, sub = tid & 3;
        const float4* xr = (const float4*)(io + (R0 + row) * 512) + sub * 32;
        float s = 0.f, ss = 0.f;
#pragma unroll
        for (int i = 0; i < 32; ++i) {
            float4 v = xr[i];
            s += (v.x + v.y) + (v.z + v.w);
            ss += (v.x * v.x + v.y * v.y) + (v.z * v.z + v.w * v.w);
        }
        s += __shfl_xor(s, 1);  ss += __shfl_xor(ss, 1);
        s += __shfl_xor(s, 2);  ss += __shfl_xor(ss, 2);
        const float mu = s * (1.f / 512.f);
        const float rs = rsqrtf(ss * (1.f / 512.f) - mu * mu + 1e-5f);
        const float4* gp = (const float4*)ln2g + sub * 32;
        const float4* bp = (const float4*)ln2b + sub * 32;
#pragma unroll
        for (int i = 0; i < 32; ++i) {
            float4 v = xr[i];
            float4 gg = gp[i];
            float4 bb = bp[i];
            const int c0 = sub * 128 + i * 4;
            h_lds[row][c0 + 0] = (__bf16)((v.x - mu) * rs * gg.x + bb.x);
            h_lds[row][c0 + 1] = (__bf16)((v.y - mu) * rs * gg.y + bb.y);
            h_lds[row][c0 + 2] = (__bf16)((v.z - mu) * rs * gg.z + bb.z);
            h_lds[row][c0 + 3] = (__bf16)((v.w - mu) * rs * gg.w + bb.w);
        }
    }
    __syncthreads();

    f32x4 oacc[8][4];
#pragma unroll
    for (int i = 0; i < 8; ++i)
#pragma unroll
        for (int m = 0; m < 4; ++m) oacc[i][m] = (f32x4){0.f, 0.f, 0.f, 0.f};

    for (int c = 0; c < 32; ++c) {
        // a1 = relu(h2 @ W1[:, c*64 .. c*64+63] + b1)
        f32x4 acc[4] = {};
        const int n1 = c * 64 + wave * 16 + lq;
#pragma unroll 2
        for (int kt = 0; kt < 16; ++kt) {
            bf16x8 bf;
            if constexpr (BF) bf = bfragT(w1T, (size_t)n1 * 512, kt * 32 + kb);
            else              bf = bfragG<2048>(W1, kt * 32 + kb, n1);
#pragma unroll
            for (int m = 0; m < 4; ++m) {
                bf16x8 af = *(const bf16x8*)&h_lds[m * 16 + lq][kt * 32 + kb];
                acc[m] = MFMA(af, bf, acc[m]);
            }
        }
        const float bia = fb1[n1];
#pragma unroll
        for (int m = 0; m < 4; ++m)
#pragma unroll
            for (int r = 0; r < 4; ++r)
                a_lds[m * 16 + g * 4 + r][wave * 16 + lq] =
                    (__bf16)fmaxf(acc[m][r] + bia, 0.f);
        __syncthreads();

        // out_acc += a1 @ W2[c*64 .. c*64+63, :]
#pragma unroll
        for (int kt = 0; kt < 2; ++kt) {
            bf16x8 af[4];
#pragma unroll
            for (int m = 0; m < 4; ++m)
                af[m] = *(const bf16x8*)&a_lds[m * 16 + lq][kt * 32 + kb];
#pragma unroll
            for (int i = 0; i < 8; ++i) {
                const int n2 = (i * 4 + wave) * 16 + lq;
                bf16x8 bf;
                if constexpr (BF) bf = bfragT(w2T, (size_t)n2 * 2048, c * 64 + kt * 32 + kb);
                else              bf = bfragG<512>(W2, c * 64 + kt * 32 + kb, n2);
#pragma unroll
                for (int m = 0; m < 4; ++m)
                    oacc[i][m] = MFMA(af[m], bf, oacc[i][m]);
            }
        }
        __syncthreads();
    }

    // ---- epilogue: io = oacc + b2 + io ----
#pragma unroll
    for (int i = 0; i < 8; ++i) {
        const int n2 = (i * 4 + wave) * 16 + lq;
        const float b2v = fb2[n2];
#pragma unroll
        for (int m = 0; m < 4; ++m)
#pragma unroll
            for (int r = 0; r < 4; ++r) {
                const size_t row = R0 + m * 16 + g * 4 + r;
                io[row * 512 + n2] = oacc[i][m][r] + b2v + io[row * 512 + n2];
            }
    }
}

extern "C" void kernel_launch(void* const* d_in, const int* in_sizes, int n_in,
                              void* d_out, int out_size, void* d_ws, size_t ws_size,
                              hipStream_t stream) {
    (void)in_sizes; (void)n_in; (void)out_size;
    const float* x   = (const float*)d_in[0];
    const float* Wq  = (const float*)d_in[1];
    const float* bq  = (const float*)d_in[2];
    const float* Wk  = (const float*)d_in[3];
    const float* bk  = (const float*)d_in[4];
    const float* Wv  = (const float*)d_in[5];
    const float* bv  = (const float*)d_in[6];
    const float* Wo  = (const float*)d_in[7];
    const float* bo  = (const float*)d_in[8];
    const float* g1  = (const float*)d_in[9];
    const float* b1  = (const float*)d_in[10];
    const float* g2  = (const float*)d_in[11];
    const float* b2  = (const float*)d_in[12];
    const float* W1  = (const float*)d_in[13];
    const float* fb1 = (const float*)d_in[14];
    const float* W2  = (const float*)d_in[15];
    const float* fb2 = (const float*)d_in[16];
    float* out = (float*)d_out;

    // bf16-transposed weight workspace layout (ushort elements):
    // qT:0  kT:262144  vT:524288  oT:786432  w1T:1048576  w2T:2097152  end:3145728
    const size_t NEED = 3145728ull * 2ull;
    if (ws_size >= NEED) {
        unsigned short* wsp = (unsigned short*)d_ws;
        unsigned short* qT  = wsp;
        unsigned short* kT  = wsp + 262144;
        unsigned short* vT  = wsp + 524288;
        unsigned short* oT  = wsp + 786432;
        unsigned short* w1T = wsp + 1048576;
        unsigned short* w2T = wsp + 2097152;
        hipLaunchKernelGGL(tKern, dim3(8, 1, 8), dim3(256), 0, stream, Wq, qT, 512, 64);
        hipLaunchKernelGGL(tKern, dim3(8, 1, 8), dim3(256), 0, stream, Wk, kT, 512, 64);
        hipLaunchKernelGGL(tKern, dim3(8, 1, 8), dim3(256), 0, stream, Wv, vT, 512, 64);
        hipLaunchKernelGGL(tKern, dim3(8, 8, 1), dim3(256), 0, stream, Wo, oT, 512, 512);
        hipLaunchKernelGGL(tKern, dim3(8, 32, 1), dim3(256), 0, stream, W1, w1T, 512, 2048);
        hipLaunchKernelGGL(tKern, dim3(32, 8, 1), dim3(256), 0, stream, W2, w2T, 2048, 512);
        hipLaunchKernelGGL((kA<true>), dim3(2048), dim3(256), 0, stream,
                           x, Wq, bq, Wk, bk, Wv, bv, Wo, bo, g1, b1,
                           qT, kT, vT, oT, out);
        hipLaunchKernelGGL((kB<true>), dim3(2048), dim3(256), 0, stream,
                           W1, fb1, W2, fb2, g2, b2, w1T, w2T, out);
    } else {
        hipLaunchKernelGGL((kA<false>), dim3(2048), dim3(256), 0, stream,
                           x, Wq, bq, Wk, bk, Wv, bv, Wo, bo, g1, b1,
                           (const unsigned short*)nullptr, (const unsigned short*)nullptr,
                           (const unsigned short*)nullptr, (const unsigned short*)nullptr, out);
        hipLaunchKernelGGL((kB<false>), dim3(2048), dim3(256), 0, stream,
                           W1, fb1, W2, fb2, g2, b2,
                           (const unsigned short*)nullptr, (const unsigned short*)nullptr, out);
    }
}